// Round 4
// baseline (328.008 us; speedup 1.0000x reference)
//
#include <hip/hip_runtime.h>
#include <math.h>

#define EPSV 1e-5f
#define B 8
#define C 1024
#define C2 512
#define RK 73
#define HW 784      // 28*28
#define QW 3136     // 56*56

typedef __attribute__((ext_vector_type(8))) short bf16x8;
typedef __attribute__((ext_vector_type(4))) float f32x4;

__device__ __forceinline__ unsigned short f2bf(float f) {
    unsigned u = __float_as_uint(f);
    return (unsigned short)((u + 0x7fffu + ((u >> 16) & 1u)) >> 16);
}
__device__ __forceinline__ float ld_f(const float* p) { return *p; }
__device__ __forceinline__ float ld_f(const unsigned short* p) {
    return __uint_as_float(((unsigned)*p) << 16);
}

// ---------- kernel 1: global average pool over y -> s0 ----------
__global__ void gap_kernel(const float* __restrict__ y, float* __restrict__ s0) {
    int bc = blockIdx.x;
    const float* p = y + (size_t)bc * QW;
    float sum = 0.f;
    for (int i = threadIdx.x; i < QW; i += 256) sum += p[i];
    for (int off = 32; off > 0; off >>= 1) sum += __shfl_down(sum, off, 64);
    __shared__ float red[4];
    if ((threadIdx.x & 63) == 0) red[threadIdx.x >> 6] = sum;
    __syncthreads();
    if (threadIdx.x == 0)
        s0[bc] = (red[0] + red[1] + red[2] + red[3]) * (1.0f / QW);
}

// ---------- kernel 2: SE FC layers ----------
__global__ void se_fc_kernel(const float* __restrict__ s0,
                             const float* __restrict__ fc1_w,
                             const float* __restrict__ fc2_w,
                             float* __restrict__ att) {
    int b = blockIdx.x;
    __shared__ float sv[C2];
    __shared__ float hv[RK];
    for (int i = threadIdx.x; i < C2; i += 256) sv[i] = s0[b * C2 + i];
    __syncthreads();
    if (threadIdx.x < RK) {
        float acc = 0.f;
        const float* wr = fc1_w + threadIdx.x * C2;
        for (int k = 0; k < C2; ++k) acc += wr[k] * sv[k];
        hv[threadIdx.x] = fmaxf(acc, 0.f);
    }
    __syncthreads();
    for (int o = threadIdx.x; o < C2; o += 256) {
        float acc = 0.f;
        const float* wr = fc2_w + o * RK;
        for (int j = 0; j < RK; ++j) acc += wr[j] * hv[j];
        att[b * C2 + o] = 1.f / (1.f + expf(-acc));
    }
}

// ---------- kernel 3: depthwise 3x3 conv + row-centered cov -> bf16 ----------
__global__ void dwcov_kernel(const float* __restrict__ x,
                             const float* __restrict__ dw_w,
                             const float* __restrict__ dw_b,
                             unsigned short* __restrict__ cov) {
    int bc = blockIdx.x;
    int c = bc & (C - 1);
    __shared__ float xs[HW];
    __shared__ float x1[HW];
    __shared__ float rm[28];
    const float* px = x + (size_t)bc * HW;
    for (int i = threadIdx.x; i < HW; i += 256) xs[i] = px[i];
    float wk[9];
#pragma unroll
    for (int j = 0; j < 9; ++j) wk[j] = dw_w[c * 9 + j];
    float bias = dw_b[c];
    __syncthreads();
    for (int p = threadIdx.x; p < HW; p += 256) {
        int h = p / 28, w = p - h * 28;
        float acc = bias;
#pragma unroll
        for (int dh = 0; dh < 3; ++dh) {
            int hh = h + dh - 1;
            if (hh < 0 || hh >= 28) continue;
#pragma unroll
            for (int dw = 0; dw < 3; ++dw) {
                int ww = w + dw - 1;
                if (ww < 0 || ww >= 28) continue;
                acc += xs[hh * 28 + ww] * wk[dh * 3 + dw];
            }
        }
        x1[p] = acc;
    }
    __syncthreads();
    if (threadIdx.x < 28) {
        float s = 0.f;
        for (int w = 0; w < 28; ++w) s += x1[threadIdx.x * 28 + w];
        rm[threadIdx.x] = s * (1.f / 28.f);
    }
    __syncthreads();
    unsigned short* pc = cov + (size_t)bc * HW;
    for (int p = threadIdx.x; p < HW; p += 256) {
        int h = p / 28, g = p - h * 28;
        float mh = rm[h], mg = rm[g];
        float acc = 0.f;
        for (int w = 0; w < 28; ++w)
            acc += (x1[h * 28 + w] - mh) * (x1[g * 28 + w] - mg);
        pc[p] = f2bf(acc * (1.f / 27.f));
    }
}

// ---------- pack weights bf16; fold bias+bn scales ----------
__global__ void pack_w(const float* __restrict__ conv_w, const float* __restrict__ conv_b,
                       const float* __restrict__ conv1_w, const float* __restrict__ conv1_b,
                       const float* __restrict__ bn_g, const float* __restrict__ bn_b,
                       const float* __restrict__ bn_m, const float* __restrict__ bn_v,
                       unsigned short* __restrict__ w0b, unsigned short* __restrict__ w1p0,
                       unsigned short* __restrict__ w1pT,
                       float* __restrict__ sA, float* __restrict__ sB0, float* __restrict__ sB1) {
    int o = blockIdx.x, t = threadIdx.x;
    for (int i = t; i < C; i += 256) w0b[(size_t)o * C + i] = f2bf(conv_w[(size_t)o * C + i]);
    for (int i = t; i < C2; i += 256) w1p0[(size_t)o * C2 + i] = f2bf(conv1_w[(size_t)o * 2048 + i]);
    for (int i = t; i < 1536; i += 256) w1pT[(size_t)o * 1536 + i] = f2bf(conv1_w[(size_t)o * 2048 + 512 + i]);
    if (t == 0) {
        float sc = rsqrtf(bn_v[o] + EPSV) * bn_g[o];
        float bi = bn_b[o] - bn_m[o] * sc;
        sA[o] = sc;
        sB0[o] = conv_b[o] * sc + bi;
        sB1[o] = conv1_b[o] * sc + bi;
    }
}

// ---------- tiled transpose+convert: src[b][rows][cols] -> dst[(b,col)][dpitch]+doff ----------
// ATT: multiply row (channel) c by att[b*rows+c] before bf16 rounding (folds SE scale).
template<typename ST, bool ATT>
__global__ __launch_bounds__(256)
void transpose_pass(const ST* __restrict__ src, unsigned short* __restrict__ dst,
                    const float* __restrict__ att,
                    int rows, int cols, int dpitch, int doff) {
    int b = blockIdx.z;
    int c0 = blockIdx.y * 64, p0 = blockIdx.x * 64;
    __shared__ float ts[64][65];
    int tid = threadIdx.x;
    int pl = tid & 63, r0 = tid >> 6;
    const ST* sb = src + ((size_t)b * rows + c0) * cols + p0;
    if (p0 + pl < cols) {
#pragma unroll
        for (int j = 0; j < 16; ++j) {
            int cl = r0 + j * 4;
            ts[cl][pl] = ld_f(&sb[(size_t)cl * cols + pl]);
        }
    }
    __syncthreads();
    int cl = tid & 63;
    float av = ATT ? att[b * rows + c0 + cl] : 1.f;
#pragma unroll
    for (int j = 0; j < 16; ++j) {
        int pl2 = r0 + j * 4;
        if (p0 + pl2 < cols)
            dst[((size_t)b * cols + p0 + pl2) * dpitch + doff + c0 + cl] = f2bf(ts[cl][pl2] * av);
    }
}

// ---------- MFMA GEMM: 64o x 64n, BK=32, 2-deep reg prefetch, raw-barrier pipeline ----------
// ALL modes now use contiguous pitch-K bf16 rows for BOTH operands: per K-step a thread
// issues just 2 global_load_dwordx4 (immediate-offset), 2 ds_write_b128, 4 ds_read_b128,
// 4 MFMA -- the issue-slot tax of strided staging (8 loads + cvt + addr VALU) is gone.
// Pipeline: two register stage-sets hold chunks i+1/i+2; loads stay in flight across
// raw s_barrier (lgkmcnt-only publish, no vmcnt(0) drain per K-step).
// XCD classes balanced & bijective: NT=49 -> 7,6*7; NT=98 -> 13,13,12*6. XCD = bx%8
// (grid.x%8==0 preserves this under blockIdx.z).
// MODE 0: A=w0b   K=1024, B=covT  [(b,p)][1024]; epi bn+sigmoid -> BcatT cols 0..511
// MODE 1: A=w1pT  K=1536, B=BcatT [(b,p)][1536]; epi f2bf -> Pb [b][o][784]
// MODE 2: A=w1p0  K=512,  B=yT    [(b,q)][512] (att folded); epi (acc+up(Pb))*bn relu -> out
template<int MODE, int K>
__global__ __launch_bounds__(256)
void mfma_gemm(const unsigned short* __restrict__ wpk,
               const unsigned short* __restrict__ bsrc,
               const unsigned short* __restrict__ Pb,
               const float* __restrict__ sA, const float* __restrict__ sB,
               void* __restrict__ outv) {
    constexpr int NIT = K / 32;                  // 16 / 32 / 48 -- all even
    constexpr int NT  = (MODE == 2) ? 49 : 98;   // n-tiles
    constexpr int QN = NT >> 3, REM = NT & 7;
    int bx = blockIdx.x;
    int r = bx & 7, ii = bx >> 3;
    int og = ii & 7, s = ii >> 3;
    int cnt = QN + (r < REM ? 1 : 0);
    if (s >= cnt) return;
    int t = (r < REM ? r * (QN + 1) : REM * (QN + 1) + (r - REM) * QN) + s;
    int o0 = og * 64;
    int n0 = t * 64;
    int b = blockIdx.z;
    union SM {
        struct { __align__(16) unsigned short Wt[2][2560]; __align__(16) unsigned short At[2][2560]; } s;
        float pt[(MODE == 2) ? 64 * 84 : 4];
    };
    __shared__ SM sm;
    int tid = threadIdx.x;
    int lane = tid & 63, wv = tid >> 6;
    int ln = lane & 15, quad = lane >> 4;
    int o_w = (wv >> 1) * 32, q_w = (wv & 1) * 32;
    int swr = tid >> 2, swk = (tid & 3) * 8;   // 16B staging: row, k-off
    const unsigned short* wg = wpk + (size_t)(o0 + swr) * K + swk;
    const unsigned short* bg = bsrc + ((size_t)((MODE == 2) ? b * QW : 0) + n0 + swr) * K + swk;

    uint4 stA_a, stA_b, stB_a, stB_b;          // two register stage-sets (A,B each)

#define LD_STAGE(P, CH) {                                                   \
        P##_a = *(const uint4*)(wg + (size_t)(CH) * 32);                    \
        P##_b = *(const uint4*)(bg + (size_t)(CH) * 32); }

#define ST_STAGE(P, BUF) {                                                  \
        *(uint4*)&sm.s.Wt[BUF][swr * 40 + swk] = P##_a;                     \
        *(uint4*)&sm.s.At[BUF][swr * 40 + swk] = P##_b; }

#define GEMM_BODY(BUF, P, CHW, CHL) {                                               \
        bf16x8 af0 = *(const bf16x8*)&sm.s.Wt[BUF][(o_w + ln) * 40 + quad * 8];     \
        bf16x8 af1 = *(const bf16x8*)&sm.s.Wt[BUF][(o_w + 16 + ln) * 40 + quad * 8];\
        bf16x8 bf0 = *(const bf16x8*)&sm.s.At[BUF][(q_w + ln) * 40 + quad * 8];     \
        bf16x8 bf1 = *(const bf16x8*)&sm.s.At[BUF][(q_w + 16 + ln) * 40 + quad * 8];\
        acc[0][0] = __builtin_amdgcn_mfma_f32_16x16x32_bf16(af0, bf0, acc[0][0], 0, 0, 0); \
        acc[0][1] = __builtin_amdgcn_mfma_f32_16x16x32_bf16(af0, bf1, acc[0][1], 0, 0, 0); \
        acc[1][0] = __builtin_amdgcn_mfma_f32_16x16x32_bf16(af1, bf0, acc[1][0], 0, 0, 0); \
        acc[1][1] = __builtin_amdgcn_mfma_f32_16x16x32_bf16(af1, bf1, acc[1][1], 0, 0, 0); \
        if ((CHW) < NIT) {                                                          \
            ST_STAGE(P, (BUF) ^ 1)                                                  \
            if ((CHL) < NIT) LD_STAGE(P, (CHL))                                     \
            asm volatile("s_waitcnt lgkmcnt(0)" ::: "memory");                      \
            __builtin_amdgcn_s_barrier();                                           \
            __builtin_amdgcn_sched_barrier(0);                                      \
        } }

    // prologue: chunk0 -> LDS[0]; chunks 1,2 in flight across the barrier
    LD_STAGE(stA, 0)
    ST_STAGE(stA, 0)
    LD_STAGE(stA, 1)
    LD_STAGE(stB, 2)
    asm volatile("s_waitcnt lgkmcnt(0)" ::: "memory");
    __builtin_amdgcn_s_barrier();
    __builtin_amdgcn_sched_barrier(0);

    f32x4 acc[2][2] = {};
    for (int i2 = 0; i2 < NIT; i2 += 2) {
        GEMM_BODY(0, stA, i2 + 1, i2 + 3)
        GEMM_BODY(1, stB, i2 + 2, i2 + 4)
    }
#undef GEMM_BODY
#undef ST_STAGE
#undef LD_STAGE

    // ---- epilogue; D: row = quad*4+reg, col = ln ----
    if (MODE == 2) {
        float* outp = (float*)outv;
        __syncthreads();
        int h0 = n0 / 56;
        int hmin = (h0 & 1) ? (h0 >> 1) : max(0, (h0 >> 1) - 1);
        for (int e = tid; e < 64 * 84; e += 256) {
            int o_l = e / 84, rem = e - o_l * 84;
            int s2 = rem / 28, w = rem - s2 * 28;
            int row = min(hmin + s2, 27);
            sm.pt[e] = ld_f(&Pb[((size_t)b * C2 + o0 + o_l) * HW + row * 28 + w]);
        }
        __syncthreads();
#pragma unroll
        for (int nt = 0; nt < 2; ++nt) {
            int q = n0 + q_w + nt * 16 + ln;
            int hq = q / 56, wq = q - hq * 56;
            int hm = hq >> 1, wm = wq >> 1;
            int hn = (hq & 1) ? min(hm + 1, 27) : max(hm - 1, 0);
            int wn_ = (wq & 1) ? min(wm + 1, 27) : max(wm - 1, 0);
            int rm_ = (hm - hmin) * 28, rn_ = (hn - hmin) * 28;
#pragma unroll
            for (int mt = 0; mt < 2; ++mt)
#pragma unroll
                for (int reg = 0; reg < 4; ++reg) {
                    int ol = o_w + mt * 16 + quad * 4 + reg;
                    int o = o0 + ol;
                    const float* Pt = &sm.pt[ol * 84];
                    float up = 0.5625f * Pt[rm_ + wm] + 0.1875f * (Pt[rm_ + wn_] + Pt[rn_ + wm])
                             + 0.0625f * Pt[rn_ + wn_];
                    float v = (acc[mt][nt][reg] + up) * sA[o] + sB[o];
                    outp[((size_t)b * C2 + o) * QW + q] = fmaxf(v, 0.f);
                }
        }
    } else if (MODE == 0) {
        unsigned short* outp = (unsigned short*)outv;   // BcatT, pitch 1536, cols 0..511
#pragma unroll
        for (int nt = 0; nt < 2; ++nt) {
            int n = n0 + q_w + nt * 16 + ln;
#pragma unroll
            for (int mt = 0; mt < 2; ++mt) {
                int ob = o0 + o_w + mt * 16 + quad * 4;
                unsigned short pk[4];
#pragma unroll
                for (int reg = 0; reg < 4; ++reg) {
                    int o = ob + reg;
                    float v = acc[mt][nt][reg] * sA[o] + sB[o];
                    pk[reg] = f2bf(1.f / (1.f + expf(-v)));
                }
                *(uint2*)&outp[(size_t)n * 1536 + ob] = *(uint2*)pk;
            }
        }
    } else {
        unsigned short* outp = (unsigned short*)outv;   // Pb [b][o][784] bf16
#pragma unroll
        for (int nt = 0; nt < 2; ++nt) {
            int n = n0 + q_w + nt * 16 + ln;
            int be = n / HW, pe = n - be * HW;
#pragma unroll
            for (int mt = 0; mt < 2; ++mt)
#pragma unroll
                for (int reg = 0; reg < 4; ++reg) {
                    int o = o0 + o_w + mt * 16 + quad * 4 + reg;
                    outp[((size_t)be * C2 + o) * HW + pe] = f2bf(acc[mt][nt][reg]);
                }
        }
    }
}

extern "C" void kernel_launch(void* const* d_in, const int* in_sizes, int n_in,
                              void* d_out, int out_size, void* d_ws, size_t ws_size,
                              hipStream_t stream) {
    const float* y       = (const float*)d_in[0];
    const float* x       = (const float*)d_in[1];
    const float* fc1_w   = (const float*)d_in[2];
    const float* fc2_w   = (const float*)d_in[3];
    const float* conv_w  = (const float*)d_in[4];
    const float* conv_b  = (const float*)d_in[5];
    const float* conv1_w = (const float*)d_in[6];
    const float* conv1_b = (const float*)d_in[7];
    const float* bn_g    = (const float*)d_in[8];
    const float* bn_b    = (const float*)d_in[9];
    const float* bn_m    = (const float*)d_in[10];
    const float* bn_v    = (const float*)d_in[11];
    const float* dw_w    = (const float*)d_in[12];
    const float* dw_b    = (const float*)d_in[13];
    float* out = (float*)d_out;

    // ---- d_out doubles as scratch for buffers that die before M2's epilogue ----
    // cov_bf(12.85M) + covT(12.85M) + BcatT(19.27M) = 44,957,696 B <= out 51,380,224 B.
    // M2 writes every out element (o: 8x64 tiles, q: 49x64 tiles exact) -> full overwrite.
    unsigned short* cov_bf = (unsigned short*)d_out;         // 8*1024*784
    unsigned short* covT   = cov_bf + (size_t)B * C * HW;    // 8*784*1024
    unsigned short* BcatT  = covT + (size_t)B * HW * C;      // 6272*1536

    // ---- ws carve: 35,297,280 B (< Round-2-proven 45,389,824 extent) ----
    float* ws  = (float*)d_ws;
    float* s0  = ws;                 // 4096
    float* att = ws + 4096;          // 4096
    float* sA  = ws + 8192;          // 512
    float* sB0 = ws + 8704;          // 512
    float* sB1 = ws + 9216;          // 512 -> header ends at float 9728 (byte 38912, 16B-aligned)
    unsigned short* w0b  = (unsigned short*)(ws + 9728);     // 512*1024 sh
    unsigned short* w1p0 = w0b + (size_t)C2 * C;             // 512*512 sh
    unsigned short* w1pT = w1p0 + (size_t)C2 * C2;           // 512*1536 sh
    unsigned short* yT   = w1pT + (size_t)C2 * 1536;         // 8*3136*512 sh
    unsigned short* Pb   = yT + (size_t)B * QW * C2;         // 8*512*784 sh

    gap_kernel<<<B * C2, 256, 0, stream>>>(y, s0);
    se_fc_kernel<<<B, 256, 0, stream>>>(s0, fc1_w, fc2_w, att);
    pack_w<<<C2, 256, 0, stream>>>(conv_w, conv_b, conv1_w, conv1_b,
                                   bn_g, bn_b, bn_m, bn_v,
                                   w0b, w1p0, w1pT, sA, sB0, sB1);
    dwcov_kernel<<<B * C, 256, 0, stream>>>(x, dw_w, dw_b, cov_bf);
    // xT: x[b][c][p] -> BcatT[(b,p)][512+c]
    transpose_pass<float, false><<<dim3(13, 16, B), 256, 0, stream>>>(
        x, BcatT, nullptr, C, HW, 1536, 512);
    // covT: cov[b][c][p] -> covT[(b,p)][c]
    transpose_pass<unsigned short, false><<<dim3(13, 16, B), 256, 0, stream>>>(
        cov_bf, covT, nullptr, C, HW, C, 0);
    // yT: y[b][c][q]*att[b][c] -> yT[(b,q)][c]  (att folded -> A of M2 is batch-independent)
    transpose_pass<float, true><<<dim3(49, 8, B), 256, 0, stream>>>(
        y, yT, att, C2, QW, C2, 0);
    // M0: x2s = sigmoid(bn(conv(cov))) -> BcatT cols 0..511
    mfma_gemm<0, 1024><<<dim3(832), 256, 0, stream>>>(w0b, covT, nullptr, sA, sB0, BcatT);
    // M1: Pb = w1[:,512:]·[x2s|x]  (bf16)
    mfma_gemm<1, 1536><<<dim3(832), 256, 0, stream>>>(w1pT, BcatT, nullptr, sA, sB0, Pb);
    // M2: out = relu(bn(w1p0·yT + up(Pb)))
    mfma_gemm<2, 512><<<dim3(448, 1, B), 256, 0, stream>>>(w1p0, yT, Pb, sA, sB1, out);
}